// Round 8
// baseline (191.238 us; speedup 1.0000x reference)
//
#include <hip/hip_runtime.h>
#include <math.h>

#define DD 1024
#define HSZ 128
#define NB 4
#define TT 2048

typedef __attribute__((ext_vector_type(8))) short bf16x8;
typedef __attribute__((ext_vector_type(4))) float f32x4;

typedef __attribute__((address_space(3))) unsigned int lds_u32_t;
typedef __attribute__((address_space(1))) unsigned int glb_u32_t;

__device__ inline void gll16(const void* g, void* l) {
    __builtin_amdgcn_global_load_lds((const glb_u32_t*)g, (lds_u32_t*)l, 16, 0, 0);
}

__device__ inline unsigned short f2bf(float f){
    unsigned u = __builtin_bit_cast(unsigned, f);
    u += 0x7fff + ((u >> 16) & 1);
    return (unsigned short)(u >> 16);
}

// ---------------- k0: prep = RoPE table + frag-linear weight tiles ----------------
// Wb' [ct8][kk16][512 chunks][8]: W[ct*64+ns*16+(l&15)][kk*64+kc*32+(l>>4)*8+j], chunk=(ns*2+kc)*64+l, ns<4
// Wo' [ct8][kk4][1024 chunks][8]: Wo[ct*128+ns*16+(l&15)][kk*64+kc*32+(l>>4)*8+j], ns<8
__global__ __launch_bounds__(256) void prep_kernel(
    const float* __restrict__ Wq, const float* __restrict__ Wk,
    const float* __restrict__ Wv, const float* __restrict__ Wo,
    unsigned short* __restrict__ Wbp, unsigned short* __restrict__ Wop,
    float2* __restrict__ tab)
{
    int bid = blockIdx.x, tid = threadIdx.x;
    if (bid < 512) {
        int i = bid * 256 + tid;
        int t = i >> 6, j = i & 63;
        float theta = __powf(10000.f, -(float)j * (1.f / 32.f));
        float ang = (float)t * theta;
        tab[i] = make_float2(__cosf(ang), __sinf(ang));
        return;
    }
    const float* s;
    unsigned short* dst;
    if (bid < 768) {
        int gc = (bid - 512) * 256 + tid;          // < 65536
        int tileid = gc >> 9;                      // 128 tiles (ct*16+kk)
        int ct = tileid >> 4, kk = tileid & 15;
        int ch = gc & 511;
        int ns = ch >> 7, kc = (ch >> 6) & 1, l6 = ch & 63;
        int wrow = ct * 64 + ns * 16 + (l6 & 15);
        int kcol = kk * 64 + kc * 32 + (l6 >> 4) * 8;
        s = (wrow < 256) ? Wq + (size_t)wrow * DD
          : (wrow < 384) ? Wk + (size_t)(wrow - 256) * DD
                         : Wv + (size_t)(wrow - 384) * DD;
        s += kcol;
        dst = Wbp + (size_t)gc * 8;
    } else {
        int gc = (bid - 768) * 256 + tid;          // < 32768
        int tileid = gc >> 10;
        int ct = tileid >> 2, kk = tileid & 3;
        int ch = gc & 1023;
        int ns = ch >> 7, kc = (ch >> 6) & 1, l6 = ch & 63;
        int orow = ct * 128 + ns * 16 + (l6 & 15);
        int kcol = kk * 64 + kc * 32 + (l6 >> 4) * 8;
        s = Wo + (size_t)orow * 256 + kcol;
        dst = Wop + (size_t)gc * 8;
    }
    float4 a = ((const float4*)s)[0];
    float4 c = ((const float4*)s)[1];
    unsigned short o[8] = {f2bf(a.x),f2bf(a.y),f2bf(a.z),f2bf(a.w),
                           f2bf(c.x),f2bf(c.y),f2bf(c.z),f2bf(c.w)};
    *(uint4*)dst = *(const uint4*)o;
}

// ---------------- k1: QKV GEMM, 128x64 tiles, rs=2, A direct, B via global_load_lds ----
// ct 0-3 -> q (h=ct>>1, col-half ct&1, RoPE); ct 4,5 -> K' halves; ct 6,7 -> V' halves.
__global__ __launch_bounds__(256) void qkv_gemm_kernel(
    const float* __restrict__ x,
    const unsigned short* __restrict__ Wbp,
    const float2* __restrict__ tab,
    unsigned short* __restrict__ qo,
    unsigned short* __restrict__ Kp,
    unsigned short* __restrict__ Vp)
{
    int bid = blockIdx.x;
    int rt = bid >> 3, ct = bid & 7;       // same-rt blocks adjacent
    int row0 = rt * 128;
    int b = row0 >> 11, t0 = row0 & (TT - 1);
    int tid = threadIdx.x;
    int wave = tid >> 6, lane = tid & 63;
    int mrow = lane & 15, quad = lane >> 4;

    __shared__ unsigned short Bs[2][4096];   // 2 x 8KB (64 cols x 64 k), frag-linear

    f32x4 acc[2][4];
    #pragma unroll
    for (int rs = 0; rs < 2; ++rs)
        #pragma unroll
        for (int ns = 0; ns < 4; ++ns)
            #pragma unroll
            for (int r = 0; r < 4; ++r) acc[rs][ns][r] = 0.f;

    const float* xr0 = x + (size_t)(row0 + wave * 32 + mrow) * DD;
    const float* xr1 = xr0 + 16 * DD;

    {
        const unsigned short* wt = Wbp + (size_t)(ct * 16) * 4096;
        gll16(wt + (size_t)(tid) * 8,        &Bs[0][((tid & 192)) * 8]);
        gll16(wt + (size_t)(256 + tid) * 8,  &Bs[0][(256 + (tid & 192)) * 8]);
    }

    for (int kk = 0; kk < 16; ++kk) {
        __syncthreads();
        if (kk < 15) {
            const unsigned short* wt = Wbp + (size_t)(ct * 16 + kk + 1) * 4096;
            unsigned short* bnext = Bs[(kk + 1) & 1];
            gll16(wt + (size_t)(tid) * 8,       bnext + ((tid & 192)) * 8);
            gll16(wt + (size_t)(256 + tid) * 8, bnext + (256 + (tid & 192)) * 8);
        }
        bf16x8 af[2][2];
        #pragma unroll
        for (int rs = 0; rs < 2; ++rs)
            #pragma unroll
            for (int kc = 0; kc < 2; ++kc) {
                const float* s = (rs ? xr1 : xr0) + kk * 64 + kc * 32 + quad * 8;
                float4 f0 = ((const float4*)s)[0];
                float4 f1 = ((const float4*)s)[1];
                bf16x8 pk;
                pk[0]=(short)f2bf(f0.x); pk[1]=(short)f2bf(f0.y); pk[2]=(short)f2bf(f0.z); pk[3]=(short)f2bf(f0.w);
                pk[4]=(short)f2bf(f1.x); pk[5]=(short)f2bf(f1.y); pk[6]=(short)f2bf(f1.z); pk[7]=(short)f2bf(f1.w);
                af[rs][kc] = pk;
            }
        const unsigned short* Bc = Bs[kk & 1];
        #pragma unroll
        for (int kc = 0; kc < 2; ++kc)
            #pragma unroll
            for (int ns = 0; ns < 4; ++ns) {
                bf16x8 bb = *(const bf16x8*)(Bc + ((ns * 2 + kc) * 64 + lane) * 8);
                #pragma unroll
                for (int rs = 0; rs < 2; ++rs)
                    acc[rs][ns] = __builtin_amdgcn_mfma_f32_16x16x32_bf16(af[rs][kc], bb, acc[rs][ns], 0, 0, 0);
            }
    }

    __syncthreads();   // Bs free for epilogue assembly

    if (ct < 4) {
        int h = ct >> 1;
        int cbase = (ct & 1) * 64;
        unsigned short* dst = qo + (size_t)(b * 2 + h) * TT * HSZ;
        #pragma unroll
        for (int rs = 0; rs < 2; ++rs)
            #pragma unroll
            for (int ns = 0; ns < 4; ++ns) {
                int colloc = cbase + ns * 16 + mrow;
                int pj = colloc >> 1;
                #pragma unroll
                for (int r = 0; r < 4; ++r) {
                    int t = t0 + wave * 32 + rs * 16 + quad * 4 + r;
                    float v = acc[rs][ns][r];
                    float vp = __shfl_xor(v, 1, 64);
                    float2 cs = tab[t * 64 + pj];
                    float outv = ((mrow & 1) == 0) ? (v * cs.x - vp * cs.y)
                                                   : (v * cs.x + vp * cs.y);
                    dst[(size_t)t * HSZ + colloc] = f2bf(outv);
                }
            }
    } else if (ct < 6) {
        // K with RoPE -> K' frag-linear tiles (this block: 128 keys x 64-dim half)
        unsigned short* A_ = &Bs[0][0];     // 8192 shorts
        int dhalf = ct - 4;
        #pragma unroll
        for (int rs = 0; rs < 2; ++rs) {
            int vw = wave * 2 + rs;
            int kt = vw >> 2, f = vw & 3;
            #pragma unroll
            for (int ns = 0; ns < 4; ++ns) {
                int d = dhalf * 64 + ns * 16 + mrow;
                int c2 = ns >> 1;
                int hi = (ns & 1) * 2 + (mrow >> 3);
                int pj = d >> 1;
                int lch = ((kt * 2 + c2) * 4 + f) * 64 + hi * 16;
                #pragma unroll
                for (int r = 0; r < 4; ++r) {
                    int t = t0 + wave * 32 + rs * 16 + quad * 4 + r;
                    float v = acc[rs][ns][r];
                    float vp = __shfl_xor(v, 1, 64);
                    float2 cs = tab[t * 64 + pj];
                    float outv = ((mrow & 1) == 0) ? (v * cs.x - vp * cs.y)
                                                   : (v * cs.x + vp * cs.y);
                    A_[(lch + quad * 4 + r) * 8 + (mrow & 7)] = f2bf(outv);
                }
            }
        }
        __syncthreads();
        #pragma unroll
        for (int u = 0; u < 4; ++u) {
            int ch = u * 256 + tid;
            int kt = ch >> 9, c2 = (ch >> 8) & 1, rest = ch & 255;
            int gch = (dhalf * 2 + c2) * 256 + rest;
            unsigned short* kd = Kp + (size_t)(b * 32 + (t0 >> 6) + kt) * 8192;
            *(uint4*)(kd + gch * 8) = *(const uint4*)(A_ + ch * 8);
        }
    } else {
        // V -> V' frag-linear tiles (this block: 128 keys x 64-dim half)
        unsigned short* A_ = &Bs[0][0];
        int dhalf = ct - 6;
        #pragma unroll
        for (int rs = 0; rs < 2; ++rs) {
            int vw = wave * 2 + rs;
            int kt = vw >> 2, p = (vw >> 1) & 1;
            int lphi = (vw & 1) * 2 + (quad >> 1);
            int j0 = (quad & 1) * 4;
            #pragma unroll
            for (int ns = 0; ns < 4; ++ns) {
                int lch = ((kt * 4 + ns) * 2 + p) * 64 + lphi * 16 + mrow;
                #pragma unroll
                for (int r = 0; r < 4; ++r)
                    A_[lch * 8 + j0 + r] = f2bf(acc[rs][ns][r]);
            }
        }
        __syncthreads();
        #pragma unroll
        for (int u = 0; u < 4; ++u) {
            int ch = u * 256 + tid;
            int kt = ch >> 9, rest = ch & 511;
            int gch = dhalf * 512 + rest;
            unsigned short* vd = Vp + (size_t)(b * 32 + (t0 >> 6) + kt) * 8192;
            *(uint4*)(vd + gch * 8) = *(const uint4*)(A_ + ch * 8);
        }
    }
}

// ---------------- k2: MFMA flash attention (exp2-domain softmax) ----------------
__global__ __launch_bounds__(256) void attn_mfma_kernel(
    const unsigned short* __restrict__ q,
    const unsigned short* __restrict__ Kp,
    const unsigned short* __restrict__ Vp,
    unsigned short* __restrict__ att)
{
    int bid = blockIdx.x;
    int rr = bid >> 3;
    int qt = (rr < 32) ? rr : 63 - (rr - 32);
    int bh = bid & 7;
    int b = bh >> 1, h = bh & 1;
    int q0 = qt * 32;
    int tid = threadIdx.x;
    int wave = tid >> 6, lane = tid & 63;
    int qsub = wave >> 1, par = wave & 1;
    int qw0 = q0 + qsub * 16;
    int mrow = lane & 15, quad = lane >> 4;

    __shared__ char raw[74240];
    unsigned short* Ks0 = (unsigned short*)raw;            // [2][8192]
    unsigned short* Vs0 = (unsigned short*)(raw + 32768);  // [2][8192]
    unsigned short* Psb = (unsigned short*)(raw + 65536);  // [4][1024]
    float* Ms_ = (float*)(raw + 73728);
    float* Ls_ = Ms_ + 32;
    float* Os  = (float*)raw;

    const unsigned short* qrow = q + (((size_t)(b * 2 + h)) * TT + qw0 + mrow) * HSZ + quad * 8;
    bf16x8 qf[4];
    #pragma unroll
    for (int c = 0; c < 4; ++c) qf[c] = *(const bf16x8*)(qrow + 32 * c);

    float mrun[4], lrun[4];
    f32x4 O[8];
    #pragma unroll
    for (int r = 0; r < 4; ++r) { mrun[r] = -1e30f; lrun[r] = 0.f; }
    #pragma unroll
    for (int g = 0; g < 8; ++g)
        #pragma unroll
        for (int r = 0; r < 4; ++r) O[g][r] = 0.f;

    const int NT = (qt + 2) >> 1;
    const float s2l = 0.08838834764831845f * 1.4426950408889634f;   // scale * log2(e)

    for (int jj = 0; jj < NT; jj += 2) {
        __syncthreads();
        for (int tp = 0; tp < 2; ++tp) {
            int j = jj + tp;
            if (j >= NT) break;
            const unsigned short* ks = Kp + (size_t)(b * 32 + j) * 8192;
            const unsigned short* vs = Vp + (size_t)(b * 32 + j) * 8192;
            #pragma unroll
            for (int u = 0; u < 4; ++u) {
                gll16(ks + (size_t)(u * 256 + tid) * 8, Ks0 + (tp * 8192) + (u * 256 + (tid & 192)) * 8);
                gll16(vs + (size_t)(u * 256 + tid) * 8, Vs0 + (tp * 8192) + (u * 256 + (tid & 192)) * 8);
            }
        }
        __syncthreads();

        int j = jj + par;
        int s0 = j * 64;
        if (j < NT && s0 <= qw0 + 15) {
            const unsigned short* Kt = Ks0 + par * 8192;
            const unsigned short* Vtt = Vs0 + par * 8192;

            f32x4 S[4];
            #pragma unroll
            for (int f = 0; f < 4; ++f)
                #pragma unroll
                for (int r = 0; r < 4; ++r) S[f][r] = 0.f;

            #pragma unroll
            for (int c = 0; c < 4; ++c)
                #pragma unroll
                for (int f = 0; f < 4; ++f) {
                    bf16x8 bk = *(const bf16x8*)(Kt + ((c * 4 + f) * 64 + lane) * 8);
                    S[f] = __builtin_amdgcn_mfma_f32_16x16x32_bf16(qf[c], bk, S[f], 0, 0, 0);
                }

            #pragma unroll
            for (int f = 0; f < 4; ++f) {
                int sg = s0 + 16 * f + mrow;
                #pragma unroll
                for (int r = 0; r < 4; ++r) {
                    int qg = qw0 + quad * 4 + r;
                    float val = S[f][r] * s2l;
                    S[f][r] = (sg <= qg) ? val : -1e30f;
                }
            }

            float al[4];
            #pragma unroll
            for (int r = 0; r < 4; ++r) {
                float v = fmaxf(fmaxf(S[0][r], S[1][r]), fmaxf(S[2][r], S[3][r]));
                v = fmaxf(v, __shfl_xor(v, 1, 64));
                v = fmaxf(v, __shfl_xor(v, 2, 64));
                v = fmaxf(v, __shfl_xor(v, 4, 64));
                v = fmaxf(v, __shfl_xor(v, 8, 64));
                float mn = fmaxf(mrun[r], v);
                al[r] = exp2f(mrun[r] - mn);
                mrun[r] = mn;
            }
            #pragma unroll
            for (int f = 0; f < 4; ++f)
                #pragma unroll
                for (int r = 0; r < 4; ++r)
                    S[f][r] = exp2f(S[f][r] - mrun[r]);
            #pragma unroll
            for (int r = 0; r < 4; ++r) {
                float v = (S[0][r] + S[1][r]) + (S[2][r] + S[3][r]);
                v += __shfl_xor(v, 1, 64);
                v += __shfl_xor(v, 2, 64);
                v += __shfl_xor(v, 4, 64);
                v += __shfl_xor(v, 8, 64);
                lrun[r] = lrun[r] * al[r] + v;
            }
            #pragma unroll
            for (int g = 0; g < 8; ++g) {
                O[g][0] *= al[0]; O[g][1] *= al[1]; O[g][2] *= al[2]; O[g][3] *= al[3];
            }

            unsigned short* Pw = Psb + wave * 1024;
            #pragma unroll
            for (int f = 0; f < 4; ++f) {
                int p = f >> 1;
                int hi2 = (2 * f + (mrow >> 3)) & 3;
                int jlo = mrow & 7;
                #pragma unroll
                for (int r = 0; r < 4; ++r)
                    Pw[(p * 64 + hi2 * 16 + quad * 4 + r) * 8 + jlo] = f2bf(S[f][r]);
            }
            bf16x8 pa[2];
            pa[0] = *(const bf16x8*)(Pw + lane * 8);
            pa[1] = *(const bf16x8*)(Pw + (64 + lane) * 8);

            #pragma unroll
            for (int g = 0; g < 8; ++g)
                #pragma unroll
                for (int p = 0; p < 2; ++p) {
                    bf16x8 bv = *(const bf16x8*)(Vtt + ((g * 2 + p) * 64 + lane) * 8);
                    O[g] = __builtin_amdgcn_mfma_f32_16x16x32_bf16(pa[p], bv, O[g], 0, 0, 0);
                }
        }
    }

    __syncthreads();
    if (par == 1) {
        if (mrow == 0) {
            #pragma unroll
            for (int r = 0; r < 4; ++r) {
                Ms_[qsub * 16 + quad * 4 + r] = mrun[r];
                Ls_[qsub * 16 + quad * 4 + r] = lrun[r];
            }
        }
        float* Ow = Os + qsub * 2048;
        #pragma unroll
        for (int g = 0; g < 8; ++g)
            #pragma unroll
            for (int r = 0; r < 4; ++r)
                Ow[(quad * 4 + r) * 128 + g * 16 + mrow] = O[g][r];
    }
    __syncthreads();
    if (par == 0) {
        const float* Op = Os + qsub * 2048;
        float A0[4], A1[4], inv[4];
        #pragma unroll
        for (int r = 0; r < 4; ++r) {
            float m1 = Ms_[qsub * 16 + quad * 4 + r];
            float l1 = Ls_[qsub * 16 + quad * 4 + r];
            float m12 = fmaxf(mrun[r], m1);
            A0[r] = exp2f(mrun[r] - m12);
            A1[r] = exp2f(m1 - m12);
            inv[r] = 1.f / (lrun[r] * A0[r] + l1 * A1[r]);
        }
        unsigned short* ab = att + (((size_t)b * TT + qw0) * 2 + h) * 128;
        #pragma unroll
        for (int g = 0; g < 8; ++g)
            #pragma unroll
            for (int r = 0; r < 4; ++r) {
                int row = quad * 4 + r;
                float o = (O[g][r] * A0[r] + Op[row * 128 + g * 16 + mrow] * A1[r]) * inv[r];
                ab[(size_t)row * 256 + g * 16 + mrow] = f2bf(o);
            }
    }
}

// ---------------- k3: outproj GEMM 128x128, rs=2, A direct from att ----------------
__global__ __launch_bounds__(256) void outproj_gemm_kernel(
    const unsigned short* __restrict__ attb,
    const unsigned short* __restrict__ Wop,
    float* __restrict__ y)
{
    int bid = blockIdx.x;
    int rt = bid >> 3, ct = bid & 7;
    int row0 = rt * 128;
    int tid = threadIdx.x;
    int wave = tid >> 6, lane = tid & 63;
    int mrow = lane & 15, quad = lane >> 4;

    __shared__ unsigned short Bs[2][8192];

    f32x4 acc[2][8];
    #pragma unroll
    for (int rs = 0; rs < 2; ++rs)
        #pragma unroll
        for (int ns = 0; ns < 8; ++ns)
            #pragma unroll
            for (int r = 0; r < 4; ++r) acc[rs][ns][r] = 0.f;

    const unsigned short* ar0 = attb + (size_t)(row0 + wave * 32 + mrow) * 256;
    const unsigned short* ar1 = ar0 + 16 * 256;

    {
        const unsigned short* wt = Wop + (size_t)(ct * 4) * 8192;
        #pragma unroll
        for (int u = 0; u < 4; ++u)
            gll16(wt + (size_t)(u * 256 + tid) * 8, &Bs[0][(u * 256 + (tid & 192)) * 8]);
    }

    for (int kk = 0; kk < 4; ++kk) {
        __syncthreads();
        if (kk < 3) {
            const unsigned short* wt = Wop + (size_t)(ct * 4 + kk + 1) * 8192;
            #pragma unroll
            for (int u = 0; u < 4; ++u)
                gll16(wt + (size_t)(u * 256 + tid) * 8, &Bs[(kk + 1) & 1][(u * 256 + (tid & 192)) * 8]);
        }
        const unsigned short* Bc = Bs[kk & 1];
        #pragma unroll
        for (int kc = 0; kc < 2; ++kc) {
            bf16x8 af0 = *(const bf16x8*)(ar0 + kk * 64 + kc * 32 + quad * 8);
            bf16x8 af1 = *(const bf16x8*)(ar1 + kk * 64 + kc * 32 + quad * 8);
            #pragma unroll
            for (int ns = 0; ns < 8; ++ns) {
                bf16x8 bb = *(const bf16x8*)(Bc + ((ns * 2 + kc) * 64 + lane) * 8);
                acc[0][ns] = __builtin_amdgcn_mfma_f32_16x16x32_bf16(af0, bb, acc[0][ns], 0, 0, 0);
                acc[1][ns] = __builtin_amdgcn_mfma_f32_16x16x32_bf16(af1, bb, acc[1][ns], 0, 0, 0);
            }
        }
    }

    #pragma unroll
    for (int rs = 0; rs < 2; ++rs)
        #pragma unroll
        for (int ns = 0; ns < 8; ++ns)
            #pragma unroll
            for (int r = 0; r < 4; ++r) {
                int row = row0 + wave * 32 + rs * 16 + quad * 4 + r;
                y[(size_t)row * DD + ct * 128 + ns * 16 + mrow] = acc[rs][ns][r];
            }
}

extern "C" void kernel_launch(void* const* d_in, const int* in_sizes, int n_in,
                              void* d_out, int out_size, void* d_ws, size_t ws_size,
                              hipStream_t stream) {
    const float* x  = (const float*)d_in[0];
    const float* Wq = (const float*)d_in[1];
    const float* Wk = (const float*)d_in[2];
    const float* Wv = (const float*)d_in[3];
    const float* Wo = (const float*)d_in[4];
    float* y = (float*)d_out;

    // ws: att 4MB | qo 4MB | K' 2MB | V' 2MB | Wb' 1MB | Wo' 0.5MB | tab 1MB
    char* ws = (char*)d_ws;
    unsigned short* at  = (unsigned short*)(ws);
    unsigned short* qo  = (unsigned short*)(ws + 4u  * 1024 * 1024);
    unsigned short* Kp  = (unsigned short*)(ws + 8u  * 1024 * 1024);
    unsigned short* Vp  = (unsigned short*)(ws + 10u * 1024 * 1024);
    unsigned short* Wbp = (unsigned short*)(ws + 12u * 1024 * 1024);
    unsigned short* Wop = (unsigned short*)(ws + 13u * 1024 * 1024);
    float2*         tb  = (float2*)        (ws + 13824u * 1024);

    prep_kernel<<<896, 256, 0, stream>>>(Wq, Wk, Wv, Wo, Wbp, Wop, tb);
    qkv_gemm_kernel<<<512, 256, 0, stream>>>(x, Wbp, tb, qo, Kp, Vp);
    attn_mfma_kernel<<<512, 256, 0, stream>>>(qo, Kp, Vp, at);
    outproj_gemm_kernel<<<512, 256, 0, stream>>>(at, Wop, y);
}